// Round 6
// baseline (773.426 us; speedup 1.0000x reference)
//
#include <hip/hip_runtime.h>
#include <math.h>

#define N_EXP 64
#define TOPK 8
#define TOPK_G 4
#define D_DIM 2048
#define BM 128
#define WAVES 8
#define THREADS 512
#define KHALF 1024
#define KW (KHALF / WAVES)   // 128 k per wave
#define BK 16                // k per staged chunk (64 B per row = 1 full line)
#define NCHUNK (KW / BK)     // 8
#define S_TOT 16384

// kernel 1: GEMM partials. grid 256 = 128 row-blocks x 2 k-halves, 512 thr,
// 1 block/CU, 2 waves/SIMD (VGPR ~220 via launch_bounds(512,1)).
// Per-thread 16x8 tile (row planes at +0/+64). LDS 96 KB, wave-private
// single buffer at [w*3072]: x [16k][128r] (2048 fl), W [16k][64e] (1024 fl).
// Global loads: 4 lanes/row, full 64B lines. Reduction overlays part[2][128][64].
__launch_bounds__(THREADS, 1)
__global__ void gemm_half_kernel(const float* __restrict__ x,
                                 const float* __restrict__ W,
                                 float* __restrict__ part)
{
    __shared__ float smem[24576];

    const int tid  = threadIdx.x;
    const int wave = tid >> 6;
    const int lane = tid & 63;
    const int lm   = lane >> 3;   // rows lm*8+i (plane A), +64 (plane B)
    const int ln   = lane & 7;    // experts ln*8+j
    const int rb   = blockIdx.x >> 1;
    const int kh   = blockIdx.x & 1;
    const int row0 = rb * BM;
    const int xb   = wave * 3072;        // x tile base
    const int wb   = xb + 2048;          // W tile base

    const int lr = lane >> 2;            // 16 rows per load instr
    const int lk = (lane & 3) * 4;       // k-quad within chunk
    const int kbase = kh * KHALF + wave * KW;

    // global sources: 4 consecutive lanes cover one row's 64B chunk line
    const float* xq = x + (size_t)(row0 + lr) * D_DIM + kbase + lk;
    const float* wq = W + (size_t)lr * D_DIM + kbase + lk;

    float accA[8][8], accB[8][8];
#pragma unroll
    for (int i = 0; i < 8; ++i)
#pragma unroll
        for (int j = 0; j < 8; ++j) { accA[i][j] = 0.f; accB[i][j] = 0.f; }

    float4 gx[8], gw[4];

#define LOADG(c) do { \
        _Pragma("unroll") \
        for (int i = 0; i < 8; ++i) \
            gx[i] = *(const float4*)(xq + (size_t)i * 16 * D_DIM + (c) * BK); \
        _Pragma("unroll") \
        for (int i = 0; i < 4; ++i) \
            gw[i] = *(const float4*)(wq + (size_t)i * 16 * D_DIM + (c) * BK); \
    } while (0)

    // LDS scatter: x float -> smem[xb + k*128 + row], W -> smem[wb + k*64 + e]
#define STOREG() do { \
        _Pragma("unroll") \
        for (int i = 0; i < 8; ++i) { \
            const int a = xb + lk * 128 + i * 16 + lr; \
            smem[a + 0 * 128] = gx[i].x; smem[a + 1 * 128] = gx[i].y; \
            smem[a + 2 * 128] = gx[i].z; smem[a + 3 * 128] = gx[i].w; \
        } \
        _Pragma("unroll") \
        for (int i = 0; i < 4; ++i) { \
            const int a = wb + lk * 64 + i * 16 + lr; \
            smem[a + 0 * 64] = gw[i].x; smem[a + 1 * 64] = gw[i].y; \
            smem[a + 2 * 64] = gw[i].z; smem[a + 3 * 64] = gw[i].w; \
        } \
    } while (0)

    LOADG(0);
    STOREG();

    for (int c = 0; c < NCHUNK; ++c) {
        if (c + 1 < NCHUNK) LOADG(c + 1);   // issue early; hidden under compute
#pragma unroll
        for (int k = 0; k < BK; ++k) {
            float fa[8], fb[8], fwv[8];
            *(float4*)&fa[0]  = *(const float4*)&smem[xb + k * 128 + lm * 8];
            *(float4*)&fa[4]  = *(const float4*)&smem[xb + k * 128 + lm * 8 + 4];
            *(float4*)&fb[0]  = *(const float4*)&smem[xb + k * 128 + 64 + lm * 8];
            *(float4*)&fb[4]  = *(const float4*)&smem[xb + k * 128 + 64 + lm * 8 + 4];
            *(float4*)&fwv[0] = *(const float4*)&smem[wb + k * 64 + ln * 8];
            *(float4*)&fwv[4] = *(const float4*)&smem[wb + k * 64 + ln * 8 + 4];
#pragma unroll
            for (int i = 0; i < 8; ++i)
#pragma unroll
                for (int j = 0; j < 8; ++j) {
                    accA[i][j] = fmaf(fa[i], fwv[j], accA[i][j]);
                    accB[i][j] = fmaf(fb[i], fwv[j], accB[i][j]);
                }
        }
        if (c + 1 < NCHUNK) STOREG();       // same-wave in-order LDS: WAR safe
    }
#undef LOADG
#undef STOREG

    // cross-wave k-reduction: 4 rounds x 2 writer waves into part[2][128][64]
    float red[16];
#pragma unroll
    for (int j = 0; j < 16; ++j) red[j] = 0.f;
    const int r2  = tid >> 2;         // 0..127
    const int eq  = (tid & 3) * 16;
    const int rsw = 4 * (r2 >> 3);

    for (int rj = 0; rj < 4; ++rj) {
        __syncthreads(); // rj=0: GEMM LDS done; else prior round reads done
        if ((wave >> 1) == rj) {
            const int p = wave & 1;
#pragma unroll
            for (int i = 0; i < 8; ++i) {
#pragma unroll
                for (int q = 0; q < 2; ++q) {
                    const int ecA = (ln * 8 + q * 4 + 4 * lm) & 63;
                    const int ecB = (ecA + 32) & 63;
                    *(float4*)&smem[p * 8192 + (lm * 8 + i) * 64 + ecA] =
                        make_float4(accA[i][q*4+0], accA[i][q*4+1], accA[i][q*4+2], accA[i][q*4+3]);
                    *(float4*)&smem[p * 8192 + (64 + lm * 8 + i) * 64 + ecB] =
                        make_float4(accB[i][q*4+0], accB[i][q*4+1], accB[i][q*4+2], accB[i][q*4+3]);
                }
            }
        }
        __syncthreads();
#pragma unroll
        for (int p = 0; p < 2; ++p) {
#pragma unroll
            for (int q = 0; q < 4; ++q) {
                const int ec = (eq + q * 4 + rsw) & 63;
                const float4 v = *(const float4*)&smem[p * 8192 + r2 * 64 + ec];
                red[q*4+0] += v.x; red[q*4+1] += v.y; red[q*4+2] += v.z; red[q*4+3] += v.w;
            }
        }
    }

    float* dst = part + ((size_t)kh * S_TOT + row0 + r2) * N_EXP + eq;
    *(float4*)(dst)      = make_float4(red[0],  red[1],  red[2],  red[3]);
    *(float4*)(dst + 4)  = make_float4(red[4],  red[5],  red[6],  red[7]);
    *(float4*)(dst + 8)  = make_float4(red[8],  red[9],  red[10], red[11]);
    *(float4*)(dst + 12) = make_float4(red[12], red[13], red[14], red[15]);
}

// kernel 2: sum halves + sigmoid + grouped top-k. 256 thr, 64 rows/block.
__global__ void select_kernel(const float* __restrict__ part,
                              const float* __restrict__ bias,
                              float* __restrict__ out_idx,
                              float* __restrict__ out_w)
{
    __shared__ float sc[64 * 65];
    __shared__ float bias_s[64];

    const int tid = threadIdx.x;
    const int r   = tid >> 2;
    const int seg = (tid & 3) * 16;
    const int row = blockIdx.x * 64 + r;

    const float* p0 = part + (size_t)row * N_EXP + seg;
    const float* p1 = p0 + (size_t)S_TOT * N_EXP;
#pragma unroll
    for (int q = 0; q < 4; ++q) {
        float4 a = *(const float4*)(p0 + q * 4);
        float4 b = *(const float4*)(p1 + q * 4);
        sc[r * 65 + seg + q * 4 + 0] = 1.0f / (1.0f + expf(-(a.x + b.x)));
        sc[r * 65 + seg + q * 4 + 1] = 1.0f / (1.0f + expf(-(a.y + b.y)));
        sc[r * 65 + seg + q * 4 + 2] = 1.0f / (1.0f + expf(-(a.z + b.z)));
        sc[r * 65 + seg + q * 4 + 3] = 1.0f / (1.0f + expf(-(a.w + b.w)));
    }
    if (tid < 64) bias_s[tid] = bias[tid];
    __syncthreads();

    if (tid < 64) {
        const int rr = tid;
        float gmax[8];
#pragma unroll
        for (int g = 0; g < 8; ++g) {
            float m = -INFINITY;
#pragma unroll
            for (int j = 0; j < 8; ++j) {
                float v = sc[rr * 65 + g * 8 + j] + bias_s[g * 8 + j];
                m = fmaxf(m, v);
            }
            gmax[g] = m;
        }
        unsigned gsel = 0;
        for (int k = 0; k < TOPK_G; ++k) {
            int best = 0; float bv = -INFINITY;
#pragma unroll
            for (int g = 0; g < 8; ++g)
                if (!((gsel >> g) & 1) && gmax[g] > bv) { bv = gmax[g]; best = g; }
            gsel |= 1u << best;
        }
        unsigned long long emask = 0ull;
#pragma unroll
        for (int g = 0; g < 8; ++g)
            if ((gsel >> g) & 1) emask |= (0xFFull << (g * 8));

        const int grow = blockIdx.x * 64 + rr;
        unsigned long long esel = 0ull;
        float wsum = 0.f;
        float wv[TOPK]; int iv[TOPK];
        for (int k = 0; k < TOPK; ++k) {
            int best = 0; float bv = -INFINITY;
            for (int e = 0; e < N_EXP; ++e) {
                if (((emask >> e) & 1) && !((esel >> e) & 1)) {
                    float v = sc[rr * 65 + e] + bias_s[e];
                    if (v > bv) { bv = v; best = e; }
                }
            }
            esel |= 1ull << best;
            iv[k] = best;
            wv[k] = sc[rr * 65 + best];
            wsum += wv[k];
        }
        const float inv = 1.0f / (wsum + 1e-20f);
#pragma unroll
        for (int k = 0; k < TOPK; ++k) {
            out_idx[grow * TOPK + k] = (float)iv[k];
            out_w[grow * TOPK + k]   = wv[k] * inv;
        }
    }
}

extern "C" void kernel_launch(void* const* d_in, const int* in_sizes, int n_in,
                              void* d_out, int out_size, void* d_ws, size_t ws_size,
                              hipStream_t stream) {
    const float* x    = (const float*)d_in[0];
    const float* W    = (const float*)d_in[1];
    const float* bias = (const float*)d_in[2];
    float* out  = (float*)d_out;
    float* part = (float*)d_ws; // 2*16384*64*4 = 8 MB scratch

    hipLaunchKernelGGL(gemm_half_kernel, dim3((S_TOT / BM) * 2), dim3(THREADS), 0, stream,
                       x, W, part);
    hipLaunchKernelGGL(select_kernel, dim3(S_TOT / 64), dim3(256), 0, stream,
                       part, bias, out, out + S_TOT * TOPK);
}

// Round 7
// 419.410 us; speedup vs baseline: 1.8441x; 1.8441x over previous
//
#include <hip/hip_runtime.h>
#include <math.h>

#define N_EXP 64
#define TOPK 8
#define TOPK_G 4
#define D_DIM 2048
#define BM 64
#define WAVES 8
#define THREADS 512
#define KHALF 1024
#define KW (KHALF / WAVES)   // 128 k per wave
#define BK 16                // 16 k per chunk: 64B per row = 1 full line
#define NCHUNK (KW / BK)     // 8
#define S_TOT 16384

// kernel 1: GEMM partials. grid 512 = 256 row-blocks x 2 k-halves, 512 thr,
// 2 blocks/CU, 4 waves/SIMD (VGPR ~120). Per-thread 8x8 tile.
// LDS 64 KB: wave w at [w*2048]: x [16k][64r] at +0, W [16k][64e] at +1024.
// Global loads line-dense: 4 lanes per row, each float4; 16 rows/instr.
// Reduction overlays part[2][64][64] at [0] (R4-proven).
__launch_bounds__(THREADS)
__global__ void gemm_half_kernel(const float* __restrict__ x,
                                 const float* __restrict__ W,
                                 float* __restrict__ part)
{
    __shared__ float smem[16384];

    const int tid  = threadIdx.x;
    const int wave = tid >> 6;
    const int lane = tid & 63;
    const int lm   = lane >> 3;   // rows lm*8+i
    const int ln   = lane & 7;    // experts ln*8+j
    const int rb   = blockIdx.x >> 1;
    const int kh   = blockIdx.x & 1;
    const int row0 = rb * BM;
    const int xb   = wave * 2048;
    const int wb   = xb + 1024;

    const int lr = lane >> 2;          // 16 rows covered per load instr
    const int lk = (lane & 3) * 4;     // k-quad within the 16k chunk
    const int kbase = kh * KHALF + wave * KW;

    const float* xq = x + (size_t)(row0 + lr) * D_DIM + kbase + lk;
    const float* wq = W + (size_t)lr * D_DIM + kbase + lk;

    float acc[8][8];
#pragma unroll
    for (int i = 0; i < 8; ++i)
#pragma unroll
        for (int j = 0; j < 8; ++j) acc[i][j] = 0.f;

    float4 gx[4], gw[4];

#define LOADG(c) do { \
        _Pragma("unroll") \
        for (int i = 0; i < 4; ++i) \
            gx[i] = *(const float4*)(xq + (size_t)i * 16 * D_DIM + (c) * BK); \
        _Pragma("unroll") \
        for (int i = 0; i < 4; ++i) \
            gw[i] = *(const float4*)(wq + (size_t)i * 16 * D_DIM + (c) * BK); \
    } while (0)

    // scatter to [k][row] / [k][expert]
#define STOREG() do { \
        _Pragma("unroll") \
        for (int i = 0; i < 4; ++i) { \
            const int a = xb + lk * 64 + i * 16 + lr; \
            smem[a + 0 * 64] = gx[i].x; smem[a + 1 * 64] = gx[i].y; \
            smem[a + 2 * 64] = gx[i].z; smem[a + 3 * 64] = gx[i].w; \
            const int b = wb + lk * 64 + i * 16 + lr; \
            smem[b + 0 * 64] = gw[i].x; smem[b + 1 * 64] = gw[i].y; \
            smem[b + 2 * 64] = gw[i].z; smem[b + 3 * 64] = gw[i].w; \
        } \
    } while (0)

    LOADG(0);
    STOREG();

    for (int c = 0; c < NCHUNK; ++c) {
        if (c + 1 < NCHUNK) LOADG(c + 1);   // issue early: hidden under compute
#pragma unroll
        for (int k = 0; k < BK; ++k) {
            float fx[8], fw[8];
            *(float4*)&fx[0] = *(const float4*)&smem[xb + k * 64 + lm * 8];
            *(float4*)&fx[4] = *(const float4*)&smem[xb + k * 64 + lm * 8 + 4];
            *(float4*)&fw[0] = *(const float4*)&smem[wb + k * 64 + ln * 8];
            *(float4*)&fw[4] = *(const float4*)&smem[wb + k * 64 + ln * 8 + 4];
#pragma unroll
            for (int i = 0; i < 8; ++i)
#pragma unroll
                for (int j = 0; j < 8; ++j)
                    acc[i][j] = fmaf(fx[i], fw[j], acc[i][j]);
        }
        if (c + 1 < NCHUNK) STOREG();       // same-wave in-order LDS: WAR safe
    }
#undef LOADG
#undef STOREG

    // cross-wave k-reduction: 4 rounds x 2 writer waves into part[2][64][64]
    float red[8];
#pragma unroll
    for (int j = 0; j < 8; ++j) red[j] = 0.f;
    const int r2 = tid >> 3;          // 0..63
    const int e0 = (tid & 7) * 8;
    const int rsw = 4 * (r2 >> 3);

    for (int rj = 0; rj < 4; ++rj) {
        __syncthreads(); // rj=0: GEMM LDS traffic done; else prior reads done
        if ((wave >> 1) == rj) {
            const int p = wave & 1;
#pragma unroll
            for (int i = 0; i < 8; ++i) {
                const int r = lm * 8 + i;
#pragma unroll
                for (int q = 0; q < 2; ++q) {
                    const int ec = (ln * 8 + q * 4 + 4 * lm) & 63; // writer swizzle
                    *(float4*)&smem[p * 4096 + r * 64 + ec] =
                        make_float4(acc[i][q*4+0], acc[i][q*4+1],
                                    acc[i][q*4+2], acc[i][q*4+3]);
                }
            }
        }
        __syncthreads();
#pragma unroll
        for (int p = 0; p < 2; ++p) {
#pragma unroll
            for (int q = 0; q < 2; ++q) {
                const int ec = (e0 + q * 4 + rsw) & 63;
                const float4 v = *(const float4*)&smem[p * 4096 + r2 * 64 + ec];
                red[q*4+0] += v.x; red[q*4+1] += v.y;
                red[q*4+2] += v.z; red[q*4+3] += v.w;
            }
        }
    }

    float* dst = part + ((size_t)kh * S_TOT + row0 + r2) * N_EXP + e0;
    *(float4*)(dst)     = make_float4(red[0], red[1], red[2], red[3]);
    *(float4*)(dst + 4) = make_float4(red[4], red[5], red[6], red[7]);
}

// kernel 2: sum halves + sigmoid + grouped top-k.
// 256 thr, 8 lanes per row -> 32 rows/block, grid 512. Parallel argmax via
// shfl_xor(width 8); ties -> lower index (matches jax.lax.top_k stability).
__global__ void select_kernel(const float* __restrict__ part,
                              const float* __restrict__ bias,
                              float* __restrict__ out_idx,
                              float* __restrict__ out_w)
{
    __shared__ float sc[32 * 68];
    __shared__ float bs[64];

    const int tid = threadIdx.x;
    const int rg  = tid >> 3;     // row within block 0..31
    const int sl  = tid & 7;      // sublane = expert-group (EPG==8)
    const int row = blockIdx.x * 32 + rg;

    if (tid < 64) bs[tid] = bias[tid];

    const float* p0 = part + (size_t)row * N_EXP + sl * 8;
    const float* p1 = p0 + (size_t)S_TOT * N_EXP;
    {
        float4 a0 = *(const float4*)(p0);
        float4 a1 = *(const float4*)(p0 + 4);
        float4 b0 = *(const float4*)(p1);
        float4 b1 = *(const float4*)(p1 + 4);
        sc[rg * 68 + sl * 8 + 0] = 1.0f / (1.0f + expf(-(a0.x + b0.x)));
        sc[rg * 68 + sl * 8 + 1] = 1.0f / (1.0f + expf(-(a0.y + b0.y)));
        sc[rg * 68 + sl * 8 + 2] = 1.0f / (1.0f + expf(-(a0.z + b0.z)));
        sc[rg * 68 + sl * 8 + 3] = 1.0f / (1.0f + expf(-(a0.w + b0.w)));
        sc[rg * 68 + sl * 8 + 4] = 1.0f / (1.0f + expf(-(a1.x + b1.x)));
        sc[rg * 68 + sl * 8 + 5] = 1.0f / (1.0f + expf(-(a1.y + b1.y)));
        sc[rg * 68 + sl * 8 + 6] = 1.0f / (1.0f + expf(-(a1.z + b1.z)));
        sc[rg * 68 + sl * 8 + 7] = 1.0f / (1.0f + expf(-(a1.w + b1.w)));
    }
    __syncthreads();

    // raw + biased scores of my group (8 experts), group max
    float raw[8], bsc[8];
    float gm = -INFINITY;
#pragma unroll
    for (int j = 0; j < 8; ++j) {
        raw[j] = sc[rg * 68 + sl * 8 + j];
        bsc[j] = raw[j] + bs[sl * 8 + j];
        gm = fmaxf(gm, bsc[j]);
    }

    // group rank among the 8 sublanes: selected iff rank < TOPK_G
    int grank = 0;
#pragma unroll
    for (int s = 1; s < 8; ++s) {
        float og = __shfl_xor(gm, s, 8);
        int   osl = sl ^ s;
        if (og > gm || (og == gm && osl < sl)) ++grank;
    }
    unsigned alive = (grank < TOPK_G) ? 0xFFu : 0u;

    // 8 passes of 8-lane argmax over remaining in-play experts
    float wsum = 0.f;
    float myw = 0.f;
    const int orow = row * TOPK;
    for (int k = 0; k < TOPK; ++k) {
        float bv = -INFINITY; int be = 9999;
#pragma unroll
        for (int j = 0; j < 8; ++j) {
            if (alive & (1u << j)) {
                if (bsc[j] > bv) { bv = bsc[j]; be = sl * 8 + j; }
            }
        }
#pragma unroll
        for (int s = 1; s < 8; s <<= 1) {
            float ov = __shfl_xor(bv, s, 8);
            int   oe = __shfl_xor(be, s, 8);
            if (ov > bv || (ov == bv && oe < be)) { bv = ov; be = oe; }
        }
        // winner be known by all 8 lanes
        const float wr = sc[rg * 68 + be];   // broadcast read
        wsum += wr;
        if ((be >> 3) == sl) alive &= ~(1u << (be & 7));
        if (sl == k) { out_idx[orow + k] = (float)be; myw = wr; }
    }
    const float inv = 1.0f / (wsum + 1e-20f);
    out_w[orow + sl] = myw * inv;
}

extern "C" void kernel_launch(void* const* d_in, const int* in_sizes, int n_in,
                              void* d_out, int out_size, void* d_ws, size_t ws_size,
                              hipStream_t stream) {
    const float* x    = (const float*)d_in[0];
    const float* W    = (const float*)d_in[1];
    const float* bias = (const float*)d_in[2];
    float* out  = (float*)d_out;
    float* part = (float*)d_ws; // 2*16384*64*4 = 8 MB scratch

    hipLaunchKernelGGL(gemm_half_kernel, dim3((S_TOT / BM) * 2), dim3(THREADS), 0, stream,
                       x, W, part);
    hipLaunchKernelGGL(select_kernel, dim3(S_TOT / 32), dim3(256), 0, stream,
                       part, bias, out, out + S_TOT * TOPK);
}

// Round 8
// 83.492 us; speedup vs baseline: 9.2635x; 5.0234x over previous
//
#include <hip/hip_runtime.h>
#include <math.h>

#define N_EXP 64
#define TOPK 8
#define TOPK_G 4
#define D_DIM 2048
#define BM 64
#define WAVES 8
#define THREADS 512
#define KHALF 1024
#define KW (KHALF / WAVES)   // 128 k per wave
#define BK 8                 // k per staged chunk
#define NCHUNK (KW / BK)     // 16
#define S_TOT 16384

// kernel 1: GEMM partials. Exactly R4's proven structure (92us, VGPR 96, no
// spill); ONLY the global-load lane mapping changed to be line-dense:
// lane -> (row = lane>>1, kquad = (lane&1)*4): 2 lanes cover 32 contiguous
// bytes of one row; one instr touches 32 full lines (vs 64 half-used).
// Block mapping kh-major: first 256 blocks all kh=0 -> per-XCD L2 reuse of W.
__launch_bounds__(THREADS)
__global__ void gemm_half_kernel(const float* __restrict__ x,
                                 const float* __restrict__ W,
                                 float* __restrict__ part)
{
    __shared__ float smem[16384];

    const int tid  = threadIdx.x;
    const int wave = tid >> 6;
    const int lane = tid & 63;
    const int lm   = lane >> 3;   // rows lm*8+i
    const int ln   = lane & 7;    // experts ln*8+j
    const int rb   = blockIdx.x & 255;   // row-block (major)
    const int kh   = blockIdx.x >> 8;    // k-half
    const int row0 = rb * BM;
    const int xb   = wave * 2048;

    const int lr2 = lane >> 1;          // 0..31 row/expert for loads
    const int lk2 = (lane & 1) * 4;     // k-quad within chunk
    const int kbase = kh * KHALF + wave * KW;

    const float* xq  = x + (size_t)(row0 + lr2) * D_DIM + kbase + lk2;
    const float* wq  = W + (size_t)lr2 * D_DIM + kbase + lk2;
    const float* xq2 = xq + (size_t)32 * D_DIM;
    const float* wq2 = wq + (size_t)32 * D_DIM;

    float acc[8][8];
#pragma unroll
    for (int i = 0; i < 8; ++i)
#pragma unroll
        for (int j = 0; j < 8; ++j) acc[i][j] = 0.f;

    float4 gx0, gx1, gw0, gw1;

#define LOADG(c) do { \
        gx0 = *(const float4*)(xq  + (c) * BK); \
        gx1 = *(const float4*)(xq2 + (c) * BK); \
        gw0 = *(const float4*)(wq  + (c) * BK); \
        gw1 = *(const float4*)(wq2 + (c) * BK); \
    } while (0)

    // scatter to [k][row] (x) / [k][expert] (W); banks = lr2, 2 lanes each: free
#define STOREG(p) do { \
        const int a = xb + (p) * 1024 + lk2 * 64 + lr2; \
        smem[a +   0] = gx0.x; smem[a +  64] = gx0.y; \
        smem[a + 128] = gx0.z; smem[a + 192] = gx0.w; \
        smem[a +  32] = gx1.x; smem[a +  96] = gx1.y; \
        smem[a + 160] = gx1.z; smem[a + 224] = gx1.w; \
        const int b = a + 512; \
        smem[b +   0] = gw0.x; smem[b +  64] = gw0.y; \
        smem[b + 128] = gw0.z; smem[b + 192] = gw0.w; \
        smem[b +  32] = gw1.x; smem[b +  96] = gw1.y; \
        smem[b + 160] = gw1.z; smem[b + 224] = gw1.w; \
    } while (0)

    // prologue: chunk 0 -> buf0; chunk 1 -> regs
    LOADG(0);
    STOREG(0);
    LOADG(1);

    for (int c = 0; c < NCHUNK; ++c) {
        if (c + 1 < NCHUNK) STOREG((c + 1) & 1);
        if (c + 2 < NCHUNK) LOADG(c + 2);
        const int cb = xb + (c & 1) * 1024;
#pragma unroll
        for (int k = 0; k < BK; ++k) {
            float fx[8], fw[8];
            *(float4*)&fx[0] = *(const float4*)&smem[cb + k * 64 + lm * 8];
            *(float4*)&fx[4] = *(const float4*)&smem[cb + k * 64 + lm * 8 + 4];
            *(float4*)&fw[0] = *(const float4*)&smem[cb + 512 + k * 64 + ln * 8];
            *(float4*)&fw[4] = *(const float4*)&smem[cb + 512 + k * 64 + ln * 8 + 4];
#pragma unroll
            for (int i = 0; i < 8; ++i)
#pragma unroll
                for (int j = 0; j < 8; ++j)
                    acc[i][j] = fmaf(fx[i], fw[j], acc[i][j]);
        }
    }
#undef LOADG
#undef STOREG

    // cross-wave k-reduction: 4 rounds x 2 writer waves into part[2][64][64]
    // (R4-proven, verbatim)
    float red[8];
#pragma unroll
    for (int j = 0; j < 8; ++j) red[j] = 0.f;
    const int r2 = tid >> 3;          // 0..63
    const int e0 = (tid & 7) * 8;
    const int rsw = 4 * (r2 >> 3);

    for (int rj = 0; rj < 4; ++rj) {
        __syncthreads(); // rj=0: GEMM LDS traffic done; else prior reads done
        if ((wave >> 1) == rj) {
            const int p = wave & 1;
#pragma unroll
            for (int i = 0; i < 8; ++i) {
                const int r = lm * 8 + i;
#pragma unroll
                for (int q = 0; q < 2; ++q) {
                    const int ec = (ln * 8 + q * 4 + 4 * lm) & 63; // writer swizzle
                    *(float4*)&smem[p * 4096 + r * 64 + ec] =
                        make_float4(acc[i][q*4+0], acc[i][q*4+1],
                                    acc[i][q*4+2], acc[i][q*4+3]);
                }
            }
        }
        __syncthreads();
#pragma unroll
        for (int p = 0; p < 2; ++p) {
#pragma unroll
            for (int q = 0; q < 2; ++q) {
                const int ec = (e0 + q * 4 + rsw) & 63;
                const float4 v = *(const float4*)&smem[p * 4096 + r2 * 64 + ec];
                red[q*4+0] += v.x; red[q*4+1] += v.y;
                red[q*4+2] += v.z; red[q*4+3] += v.w;
            }
        }
    }

    float* dst = part + ((size_t)kh * S_TOT + row0 + r2) * N_EXP + e0;
    *(float4*)(dst)     = make_float4(red[0], red[1], red[2], red[3]);
    *(float4*)(dst + 4) = make_float4(red[4], red[5], red[6], red[7]);
}

// kernel 2: sum halves + sigmoid + grouped top-k. R7-proven (ran, absmax 0).
// 256 thr, 8 lanes per row -> 32 rows/block, grid 512. Parallel argmax via
// shfl_xor(width 8); ties -> lower index (matches jax.lax.top_k stability).
__global__ void select_kernel(const float* __restrict__ part,
                              const float* __restrict__ bias,
                              float* __restrict__ out_idx,
                              float* __restrict__ out_w)
{
    __shared__ float sc[32 * 68];
    __shared__ float bs[64];

    const int tid = threadIdx.x;
    const int rg  = tid >> 3;     // row within block 0..31
    const int sl  = tid & 7;      // sublane = expert-group (EPG==8)
    const int row = blockIdx.x * 32 + rg;

    if (tid < 64) bs[tid] = bias[tid];

    const float* p0 = part + (size_t)row * N_EXP + sl * 8;
    const float* p1 = p0 + (size_t)S_TOT * N_EXP;
    {
        float4 a0 = *(const float4*)(p0);
        float4 a1 = *(const float4*)(p0 + 4);
        float4 b0 = *(const float4*)(p1);
        float4 b1 = *(const float4*)(p1 + 4);
        sc[rg * 68 + sl * 8 + 0] = 1.0f / (1.0f + expf(-(a0.x + b0.x)));
        sc[rg * 68 + sl * 8 + 1] = 1.0f / (1.0f + expf(-(a0.y + b0.y)));
        sc[rg * 68 + sl * 8 + 2] = 1.0f / (1.0f + expf(-(a0.z + b0.z)));
        sc[rg * 68 + sl * 8 + 3] = 1.0f / (1.0f + expf(-(a0.w + b0.w)));
        sc[rg * 68 + sl * 8 + 4] = 1.0f / (1.0f + expf(-(a1.x + b1.x)));
        sc[rg * 68 + sl * 8 + 5] = 1.0f / (1.0f + expf(-(a1.y + b1.y)));
        sc[rg * 68 + sl * 8 + 6] = 1.0f / (1.0f + expf(-(a1.z + b1.z)));
        sc[rg * 68 + sl * 8 + 7] = 1.0f / (1.0f + expf(-(a1.w + b1.w)));
    }
    __syncthreads();

    // raw + biased scores of my 8 experts, group max
    float bsc[8];
    float gm = -INFINITY;
#pragma unroll
    for (int j = 0; j < 8; ++j) {
        bsc[j] = sc[rg * 68 + sl * 8 + j] + bs[sl * 8 + j];
        gm = fmaxf(gm, bsc[j]);
    }

    // group rank among the 8 sublanes: selected iff rank < TOPK_G
    int grank = 0;
#pragma unroll
    for (int s = 1; s < 8; ++s) {
        float og = __shfl_xor(gm, s, 8);
        int   osl = sl ^ s;
        if (og > gm || (og == gm && osl < sl)) ++grank;
    }
    unsigned alive = (grank < TOPK_G) ? 0xFFu : 0u;

    // 8 passes of 8-lane argmax over remaining in-play experts
    float wsum = 0.f;
    float myw = 0.f;
    const int orow = row * TOPK;
    for (int k = 0; k < TOPK; ++k) {
        float bv = -INFINITY; int be = 9999;
#pragma unroll
        for (int j = 0; j < 8; ++j) {
            if (alive & (1u << j)) {
                if (bsc[j] > bv) { bv = bsc[j]; be = sl * 8 + j; }
            }
        }
#pragma unroll
        for (int s = 1; s < 8; s <<= 1) {
            float ov = __shfl_xor(bv, s, 8);
            int   oe = __shfl_xor(be, s, 8);
            if (ov > bv || (ov == bv && oe < be)) { bv = ov; be = oe; }
        }
        const float wr = sc[rg * 68 + be];   // broadcast read of raw score
        wsum += wr;
        if ((be >> 3) == sl) alive &= ~(1u << (be & 7));
        if (sl == k) { out_idx[orow + k] = (float)be; myw = wr; }
    }
    const float inv = 1.0f / (wsum + 1e-20f);
    out_w[orow + sl] = myw * inv;
}

extern "C" void kernel_launch(void* const* d_in, const int* in_sizes, int n_in,
                              void* d_out, int out_size, void* d_ws, size_t ws_size,
                              hipStream_t stream) {
    const float* x    = (const float*)d_in[0];
    const float* W    = (const float*)d_in[1];
    const float* bias = (const float*)d_in[2];
    float* out  = (float*)d_out;
    float* part = (float*)d_ws; // 2*16384*64*4 = 8 MB scratch

    hipLaunchKernelGGL(gemm_half_kernel, dim3((S_TOT / BM) * 2), dim3(THREADS), 0, stream,
                       x, W, part);
    hipLaunchKernelGGL(select_kernel, dim3(S_TOT / 32), dim3(256), 0, stream,
                       part, bias, out, out + S_TOT * TOPK);
}